// Round 1
// baseline (424.118 us; speedup 1.0000x reference)
//
#include <hip/hip_runtime.h>
#include <stdint.h>

typedef __attribute__((ext_vector_type(8))) short bf16x8;
typedef __attribute__((ext_vector_type(4))) float f32x4;
typedef __attribute__((ext_vector_type(4))) unsigned short u16x4;
typedef __attribute__((ext_vector_type(4))) unsigned int u32x4;

#define NB 32
#define HH 128
#define WW 128
#define CI 128
#define CO 128
#define HO 126
#define WO 126
#define TH 16
#define TW 16
#define PHh 18
#define PWw 18
#define NROW (PHh * PWw)   // 324 patch rows
#define RSTR 40            // shorts per LDS row (80 B padded; bank-rotates like the old XOR swizzle)
#define QBUF (NROW * RSTR) // 12960 shorts = 25920 B per quarter buffer

__device__ __forceinline__ unsigned short f2bf(float f) {
  union { float f; unsigned u; } x; x.f = f;
  unsigned u = x.u;
  u += 0x7FFFu + ((u >> 16) & 1u);   // RNE round to bf16
  return (unsigned short)(u >> 16);
}

__device__ __forceinline__ unsigned cvtpk_bf16(float a, float b) {
  unsigned r;
  asm("v_cvt_pk_bf16_f32 %0, %1, %2" : "=v"(r) : "v"(a), "v"(b));
  return r;  // low16 = bf16(a), high16 = bf16(b)
}

// prep: [b,p][ci][co] f32 -> fragment-blocked bf16, slice-major [b][ch][p][kc]:
//   slice = (ch*9+p)*2+kc (4096 shorts each); within: f*512 + lane*8 + e
//   holds kin[b,p][ci = ch*64+kc*32+(lane>>4)*8+e][co = (f>>2)*64+(f&3)*16+(lane&15)]
__global__ void prep_kt(const float* __restrict__ kin, unsigned short* __restrict__ ktr) {
  __shared__ unsigned short t[CI * CO];  // 32 KB
  int bp = blockIdx.x;  // b*9+p, 0..287
  int b = bp / 9, p = bp % 9;
  const float* src = kin + (size_t)bp * (CI * CO);
  unsigned short* dstb = ktr + (size_t)b * (9 * CI * CO);
  for (int i = threadIdx.x; i < CI * CO / 4; i += blockDim.x) {
    f32x4 v = *(const f32x4*)(src + i * 4);
    u16x4 o;
    o.x = f2bf(v.x); o.y = f2bf(v.y); o.z = f2bf(v.z); o.w = f2bf(v.w);
    *(u16x4*)&t[i * 4] = o;
  }
  __syncthreads();
  for (int j = threadIdx.x; j < 2048; j += blockDim.x) {  // j = (sl*8+f)*64+lane
    int lane = j & 63, f = (j >> 6) & 7, sl = j >> 9;     // sl = ch*2+kc
    int ch = sl >> 1, kc = sl & 1;
    int co = (f >> 2) * 64 + (f & 3) * 16 + (lane & 15);
    int ci0 = ch * 64 + kc * 32 + (lane >> 4) * 8;
    bf16x8 v;
#pragma unroll
    for (int e = 0; e < 8; ++e) v[e] = t[(ci0 + e) * CO + co];
    int slice = (ch * 9 + p) * 2 + kc;
    *(bf16x8*)&dstb[(size_t)slice * 4096 + f * 512 + lane * 8] = v;
  }
}

// naive fallback (only if ws_size too small — not expected on this harness)
__global__ void conv_naive(const float* __restrict__ X, const float* __restrict__ Kf,
                           float* __restrict__ out) {
  int idx = blockIdx.x * blockDim.x + threadIdx.x;           // over B*HO*WO*CO
  if (idx >= NB * HO * WO * CO) return;
  int co = idx & 127, t = idx >> 7;
  int wp = t % WO; t /= WO;
  int hp = t % HO; int b = t / HO;
  const float* xb = X + (size_t)b * HH * WW * CI;
  const float* kb = Kf + (size_t)b * 9 * CI * CO;
  float s = 0.f;
  for (int p = 0; p < 9; ++p) {
    int kh = p / 3, kw = p % 3;
    const float* xr = xb + ((size_t)(hp + kh) * WW + (wp + kw)) * CI;
    const float* kr = kb + (size_t)p * CI * CO + co;
    for (int ci = 0; ci < CI; ++ci) s += xr[ci] * kr[(size_t)ci * CO];
  }
  out[idx] = s;
}

__global__ __launch_bounds__(512, 4) void conv_main(
    const float* __restrict__ X, const unsigned short* __restrict__ Kt,
    float* __restrict__ out) {
  // Double-buffered quarter-ci (32 ci) patch tiles. Row stride padded to 80 B:
  // bank group of granule (row,ks) = (row*20 + ks*4) & 31 -> same 2-per-bank
  // multiplicity per 16-lane phase as the old XOR swizzle (measured 0 conflicts),
  // but ds_read addresses are base + compile-time immediate (no swizzle VALU).
  __shared__ unsigned short lds_a[2][QBUF];  // 51840 B -> 2-3 blocks/CU

  const int tid = threadIdx.x;
  const int lane = tid & 63;
  const int wid = tid >> 6;            // 8 waves, 4 (h) x 2 (co)
  const int wr = wid >> 1, wc = wid & 1;

  // XCD-clustered block swizzle (verified R3: FETCH 200->146MB).
  const int l = blockIdx.x;            // 0..2047
  const int xcd = l & 7, j = l >> 3;   // j: 0..255
  const int b = xcd * 4 + (j >> 6);    // 4 batches per XCD
  const int t = j & 63;                // tile within batch (8x8 of 16x16)
  const int ht = t >> 3, wt = t & 7;
  const int h0 = ht * TH, w0 = wt * TW;
  const int ks = lane >> 4, lr = lane & 15;

  const float* xb = X + (size_t)b * HH * WW * CI;

  // ---- per-thread staging granules: 3 x (8 ci = 32 B fp32 -> 16 B bf16) ----
  // granule id s = row*4 + g; ci = q*32 + g*8 + e (q = quarter, set at issue)
  int sdst[3]; const float* ssrc[3]; bool sz[3];
#pragma unroll
  for (int i = 0; i < 3; ++i) {
    int s = tid + i * 512;
    int row = s >> 2, g = s & 3;
    int h = row / PWw, w = row - h * PWw;
    int gh = h0 + h, gw = w0 + w;
    sdst[i] = (s < NROW * 4) ? (row * RSTR + g * 8) : -1;   // -1: no such granule
    sz[i] = (gh >= HH) | (gw >= WW);                        // zero-fill halo
    ssrc[i] = xb + ((size_t)((gh & 127) * WW + (gw & 127))) * CI + g * 8;
  }

  // A-fragment LDS short-offsets per m; step p adds immediate d_p*RSTR
  int aoff[4];
#pragma unroll
  for (int m = 0; m < 4; ++m)
    aoff[m] = ((wr * 4 + m) * PWw + lr) * RSTR + ks * 8;

  // B: slice = (ch*9+p)*2+kc = ((q>>1)*9+p)*2+(q&1); wave reads 4 contiguous 1KB frags
  const unsigned short* ktw = Kt + (size_t)b * 9 * CI * CO + (wc * 4) * 512 + lane * 8;

  const f32x4 zero4 = {0.f, 0.f, 0.f, 0.f};

  auto sissue = [&](int i, int q, f32x4& lo, f32x4& hi) {
    lo = zero4; hi = zero4;
    if (sdst[i] >= 0 && !sz[i]) {
      const float* p = ssrc[i] + q * 32;
      lo = *(const f32x4*)p;
      hi = *(const f32x4*)(p + 4);
    }
  };
  auto swrite = [&](int i, unsigned short* wb, const f32x4& lo, const f32x4& hi) {
    if (sdst[i] >= 0) {
      u32x4 r;
      r.x = cvtpk_bf16(lo.x, lo.y);
      r.y = cvtpk_bf16(lo.z, lo.w);
      r.z = cvtpk_bf16(hi.x, hi.y);
      r.w = cvtpk_bf16(hi.z, hi.w);
      *(u32x4*)&wb[sdst[i]] = r;
    }
  };

  bf16x8 Hf[4];
  auto loadB = [&](const unsigned short* p) {
#pragma unroll
    for (int n = 0; n < 4; ++n)
      Hf[n] = *(const bf16x8*)(p + n * 512);   // n*1024B fits offset imm
  };

  // ---- prologue: stage quarter 0 into buf0, prefetch B(q0,p0) ----
  {
    f32x4 al, ah, bl, bh;
    sissue(0, 0, al, ah);
    sissue(1, 0, bl, bh);
    loadB(ktw);                        // slice 0
    swrite(0, lds_a[0], al, ah);
    sissue(2, 0, al, ah);
    swrite(1, lds_a[0], bl, bh);
    swrite(2, lds_a[0], al, ah);
  }
  __syncthreads();

  f32x4 acc[4][4];
#pragma unroll
  for (int m = 0; m < 4; ++m)
#pragma unroll
    for (int n = 0; n < 4; ++n) acc[m][n] = zero4;

  f32x4 glo, ghi;                      // one staging granule in flight
  const unsigned short* bptr = ktw;    // currently-loaded slice pointer

#pragma unroll 1
  for (int q = 0; q < 4; ++q) {
    const unsigned short* rb = lds_a[q & 1];
    unsigned short* wb = lds_a[(q & 1) ^ 1];
    const bool st = (q < 3);
#pragma unroll
    for (int p = 0; p < 9; ++p) {
      const int kh = p / 3, kw = p % 3;
      const int dp = (kh * PWw + kw) * RSTR;     // compile-time per p
      // issue next-quarter granule loads early (T14: issue@{0,3,6}, write@{2,5,8})
      if (st && p == 0) sissue(0, q + 1, glo, ghi);
      if (st && p == 3) sissue(1, q + 1, glo, ghi);
      if (st && p == 6) sissue(2, q + 1, glo, ghi);

      bf16x8 af[4];
#pragma unroll
      for (int m = 0; m < 4; ++m)
        af[m] = *(const bf16x8*)&rb[aoff[m] + dp];

      __builtin_amdgcn_s_setprio(1);
#pragma unroll
      for (int m = 0; m < 4; ++m)
#pragma unroll
        for (int n = 0; n < 4; ++n)
          acc[m][n] = __builtin_amdgcn_mfma_f32_16x16x32_bf16(af[m], Hf[n], acc[m][n], 0, 0, 0);
      __builtin_amdgcn_s_setprio(0);

      // B prefetch for next step (WAR on Hf is safe: MFMAs already issued)
      if (p < 8) {
        bptr += 8192;                  // +2 slices (kc stride) in shorts
        loadB(bptr);
      } else if (q < 3) {
        int q2 = q + 1;
        bptr = ktw + (size_t)((q2 >> 1) * 18 + (q2 & 1)) * 4096;
        loadB(bptr);
      }

      // convert + LDS-write the in-flight granule (2-step load->use gap,
      // vmcnt wait lands after an MFMA cluster is queued)
      if (st && p == 2) swrite(0, wb, glo, ghi);
      if (st && p == 5) swrite(1, wb, glo, ghi);
      if (st && p == 8) swrite(2, wb, glo, ghi);
    }
    if (q < 3) __syncthreads();
  }

  // ---- epilogue: C/D map col=lane&15 (cout), row=(lane>>4)*4+reg (pw) ----
  float* ob = out + (size_t)b * HO * WO * CO;
#pragma unroll
  for (int m = 0; m < 4; ++m) {
    int hp = h0 + wr * 4 + m;
    if (hp >= HO) continue;
#pragma unroll
    for (int r = 0; r < 4; ++r) {
      int wp = w0 + ks * 4 + r;
      if (wp >= WO) continue;
#pragma unroll
      for (int n = 0; n < 4; ++n) {
        int co = wc * 64 + n * 16 + lr;
        ob[((size_t)hp * WO + wp) * CO + co] = acc[m][n][r];
      }
    }
  }
}

extern "C" void kernel_launch(void* const* d_in, const int* in_sizes, int n_in,
                              void* d_out, int out_size, void* d_ws, size_t ws_size,
                              hipStream_t stream) {
  const float* X = (const float*)d_in[0];
  const float* Kf = (const float*)d_in[1];
  float* out = (float*)d_out;
  size_t need = (size_t)NB * 9 * CI * CO * sizeof(unsigned short);  // 9.4 MB
  if (d_ws != nullptr && ws_size >= need) {
    unsigned short* ktr = (unsigned short*)d_ws;
    prep_kt<<<dim3(NB * 9), 256, 0, stream>>>(Kf, ktr);
    conv_main<<<dim3(2048), 512, 0, stream>>>(X, ktr, out);
  } else {
    int total = NB * HO * WO * CO;
    conv_naive<<<(total + 255) / 256, 256, 0, stream>>>(X, Kf, out);
  }
}

// Round 2
// 250.588 us; speedup vs baseline: 1.6925x; 1.6925x over previous
//
#include <hip/hip_runtime.h>
#include <stdint.h>

typedef __attribute__((ext_vector_type(8))) short bf16x8;
typedef __attribute__((ext_vector_type(4))) float f32x4;
typedef __attribute__((ext_vector_type(4))) unsigned short u16x4;

#define NB 32
#define HH 128
#define WW 128
#define CI 128
#define CO 128
#define HO 126
#define WO 126
#define TH 8            // output tile h (4-wave blocks)
#define TW 16           // output tile w (locked: MFMA M=16 maps to w)
#define PHh 10          // patch h = TH + 2
#define PWw 18          // patch w = TW + 2
#define NROW (PHh * PWw)      // 180 patch rows
#define NSLOT (NROW * 16)     // 2880 f32x4 stage slots per ci-half

__device__ __forceinline__ unsigned short f2bf(float f) {
  union { float f; unsigned u; } x; x.f = f;
  unsigned u = x.u;
  u += 0x7FFFu + ((u >> 16) & 1u);   // RNE round to bf16
  return (unsigned short)(u >> 16);
}

// XOR-swizzle for 128B (64-short) rows: short-idx ^= ((row&7)<<3), row = idx>>6
// (measured 0 bank conflicts in the 512-thread ancestor; byte ^= (row&7)<<4)
__device__ __forceinline__ int swz64(int idx) { return idx ^ (((idx >> 6) & 7) << 3); }

// prep: [b,p][ci][co] f32 -> fragment-blocked bf16, slice-major [b][ch][p][kc]:
//   slice = (ch*9+p)*2+kc (4096 shorts each); within: f*512 + lane*8 + e
//   holds kin[b,p][ci = ch*64+kc*32+(lane>>4)*8+e][co = (f>>2)*64+(f&3)*16+(lane&15)]
__global__ void prep_kt(const float* __restrict__ kin, unsigned short* __restrict__ ktr) {
  __shared__ unsigned short t[CI * CO];  // 32 KB
  int bp = blockIdx.x;  // b*9+p, 0..287
  int b = bp / 9, p = bp % 9;
  const float* src = kin + (size_t)bp * (CI * CO);
  unsigned short* dstb = ktr + (size_t)b * (9 * CI * CO);
  for (int i = threadIdx.x; i < CI * CO / 4; i += blockDim.x) {
    f32x4 v = *(const f32x4*)(src + i * 4);
    u16x4 o;
    o.x = f2bf(v.x); o.y = f2bf(v.y); o.z = f2bf(v.z); o.w = f2bf(v.w);
    *(u16x4*)&t[i * 4] = o;
  }
  __syncthreads();
  for (int j = threadIdx.x; j < 2048; j += blockDim.x) {  // j = (sl*8+f)*64+lane
    int lane = j & 63, f = (j >> 6) & 7, sl = j >> 9;     // sl = ch*2+kc
    int ch = sl >> 1, kc = sl & 1;
    int co = (f >> 2) * 64 + (f & 3) * 16 + (lane & 15);
    int ci0 = ch * 64 + kc * 32 + (lane >> 4) * 8;
    bf16x8 v;
#pragma unroll
    for (int e = 0; e < 8; ++e) v[e] = t[(ci0 + e) * CO + co];
    int slice = (ch * 9 + p) * 2 + kc;
    *(bf16x8*)&dstb[(size_t)slice * 4096 + f * 512 + lane * 8] = v;
  }
}

// naive fallback (only if ws_size too small — not expected on this harness)
__global__ void conv_naive(const float* __restrict__ X, const float* __restrict__ Kf,
                           float* __restrict__ out) {
  int idx = blockIdx.x * blockDim.x + threadIdx.x;           // over B*HO*WO*CO
  if (idx >= NB * HO * WO * CO) return;
  int co = idx & 127, t = idx >> 7;
  int wp = t % WO; t /= WO;
  int hp = t % HO; int b = t / HO;
  const float* xb = X + (size_t)b * HH * WW * CI;
  const float* kb = Kf + (size_t)b * 9 * CI * CO;
  float s = 0.f;
  for (int p = 0; p < 9; ++p) {
    int kh = p / 3, kw = p % 3;
    const float* xr = xb + ((size_t)(hp + kh) * WW + (wp + kw)) * CI;
    const float* kr = kb + (size_t)p * CI * CO + co;
    for (int ci = 0; ci < CI; ++ci) s += xr[ci] * kr[(size_t)ci * CO];
  }
  out[idx] = s;
}

// 4-wave blocks: 4 independent barrier groups per CU (vs 2 with 8-wave blocks)
// so one block's stage phase hides under three others' MFMA phases.
__global__ __launch_bounds__(256, 4) void conv_main(
    const float* __restrict__ X, const unsigned short* __restrict__ Kt,
    float* __restrict__ out) {
  // One ci-half of the 10x18 input patch, swizzled 128B rows. 23040 B ->
  // 4 blocks/CU (LDS 92 KB; regs: 60 VGPR + 64 acc = 124 -> 4 waves/SIMD).
  __shared__ unsigned short lds_a[NROW * 64];

  const int tid = threadIdx.x;
  const int lane = tid & 63;
  const int wid = tid >> 6;            // 4 waves, 2 (h) x 2 (co)
  const int wr = wid >> 1, wc = wid & 1;

  // XCD-clustered block swizzle: give each XCD 4 whole batches so its B
  // working set stays L2-resident (verified: FETCH 200->146MB in ancestor).
  const int l = blockIdx.x;            // 0..4095
  const int xcd = l & 7, j = l >> 3;   // j: 0..511
  const int b = xcd * 4 + (j >> 7);    // 4 batches per XCD
  const int t = j & 127;               // tile within batch (16h x 8w)
  const int ht = t >> 3, wt = t & 7;
  const int h0 = ht * TH, w0 = wt * TW;
  const int ks = lane >> 4, lr = lane & 15;

  const float* xb = X + (size_t)b * HH * WW * CI;

  // ---- stage one ci-half: depth-4 software-pipelined, fully unrolled ----
  // slot s = row*16 + ci4; per-thread slots s = tid + k*256, k = 0..11
  f32x4 sv[4]; int sdd[4];
  auto sissue = [&](int k, int jj, int ch) {
    int s = tid + (k << 8);
    bool valid = s < NSLOT;
    int ci4 = s & 15, row = s >> 4;
    int h = row / PWw, w = row - h * PWw;
    int gh = h0 + h, gw = w0 + w;
    f32x4 v = {0.f, 0.f, 0.f, 0.f};
    if (valid && gh < HH && gw < WW)
      v = *(const f32x4*)(xb + ((size_t)(gh * WW + gw)) * CI + ch * 64 + ci4 * 4);
    sv[jj] = v;
    sdd[jj] = valid ? swz64(row * 64 + ci4 * 4) : -1;
  };
  auto swrite = [&](int jj) {
    if (sdd[jj] >= 0) {
      f32x4 v = sv[jj];
      u16x4 o;
      o.x = f2bf(v.x); o.y = f2bf(v.y); o.z = f2bf(v.z); o.w = f2bf(v.w);
      *(u16x4*)&lds_a[sdd[jj]] = o;
    }
  };
  auto stageA = [&](int ch) {
    sissue(0, 0, ch); sissue(1, 1, ch); sissue(2, 2, ch); sissue(3, 3, ch);
#pragma unroll
    for (int k = 0; k < 12; ++k) {
      swrite(k & 3);                       // consumes sv[k&3]
      if (k + 4 < 12) sissue(k + 4, (k + 4) & 3, ch);
    }
  };

  f32x4 zero = {0.f, 0.f, 0.f, 0.f};
  f32x4 acc[4][4];
#pragma unroll
  for (int m = 0; m < 4; ++m)
#pragma unroll
    for (int n = 0; n < 4; ++n) acc[m][n] = zero;

  // B slices: slice = (ch*9+p)*2+kc; each wave loads its 4 co-fragments
  // (wc half) = 4 contiguous 1KB bursts (L2-resident after XCD clustering).
  const unsigned short* ktw = Kt + (size_t)b * 9 * CI * CO + (wc * 4) * 512 + lane * 8;

  // Single B buffer (16 VGPR): the load for step s+1 has only a WAR dep on
  // cluster-s MFMA *issues*, so it issues a full MFMA-cluster ahead of its
  // use — covers the ~200 cyc L2 hit; TLP covers the rest.
  bf16x8 Hf[4];
  auto loadBh = [&](int slice) {
#pragma unroll
    for (int n = 0; n < 4; ++n)
      Hf[n] = *(const bf16x8*)&ktw[(size_t)slice * 4096 + n * 512];
  };

  // One half-step: 4 LDS A-frag reads + 16 MFMA against register B-frags.
  auto comph = [&](int s) {            // s = p*2+kc within the ch pass
    int p = s >> 1, kc = s & 1;
    int kh = p < 3 ? 0 : (p < 6 ? 1 : 2);
    int kw = p - kh * 3;
    bf16x8 af[4];
#pragma unroll
    for (int m = 0; m < 4; ++m) {
      int row = (wr * 4 + m + kh) * PWw + lr + kw;
      af[m] = *(const bf16x8*)&lds_a[swz64(row * 64 + kc * 32 + ks * 8)];
    }
    __builtin_amdgcn_s_setprio(1);
#pragma unroll
    for (int m = 0; m < 4; ++m)
#pragma unroll
      for (int n = 0; n < 4; ++n)
        acc[m][n] = __builtin_amdgcn_mfma_f32_16x16x32_bf16(af[m], Hf[n], acc[m][n], 0, 0, 0);
    __builtin_amdgcn_s_setprio(0);
  };

#pragma unroll 1
  for (int ch = 0; ch < 2; ++ch) {
    if (ch) __syncthreads();           // all waves done reading previous half
    stageA(ch);
    loadBh(ch * 18);
    __syncthreads();                   // lds_a ready
#pragma unroll 1
    for (int s = 0; s < 18; ++s) {
      comph(s);
      if (s + 1 < 18) loadBh(ch * 18 + s + 1);
    }
  }

  // ---- epilogue: C/D map col=lane&15 (cout), row=(lane>>4)*4+reg (pw) ----
  float* ob = out + (size_t)b * HO * WO * CO;
#pragma unroll
  for (int m = 0; m < 4; ++m) {
    int hp = h0 + wr * 4 + m;
    if (hp >= HO) continue;
#pragma unroll
    for (int r = 0; r < 4; ++r) {
      int wp = w0 + ks * 4 + r;
      if (wp >= WO) continue;
#pragma unroll
      for (int n = 0; n < 4; ++n) {
        int co = wc * 64 + n * 16 + lr;
        ob[((size_t)hp * WO + wp) * CO + co] = acc[m][n][r];
      }
    }
  }
}

extern "C" void kernel_launch(void* const* d_in, const int* in_sizes, int n_in,
                              void* d_out, int out_size, void* d_ws, size_t ws_size,
                              hipStream_t stream) {
  const float* X = (const float*)d_in[0];
  const float* Kf = (const float*)d_in[1];
  float* out = (float*)d_out;
  size_t need = (size_t)NB * 9 * CI * CO * sizeof(unsigned short);  // 9.4 MB
  if (d_ws != nullptr && ws_size >= need) {
    unsigned short* ktr = (unsigned short*)d_ws;
    prep_kt<<<dim3(NB * 9), 256, 0, stream>>>(Kf, ktr);
    conv_main<<<dim3(4096), 256, 0, stream>>>(X, ktr, out);
  } else {
    int total = NB * HO * WO * CO;
    conv_naive<<<(total + 255) / 256, 256, 0, stream>>>(X, Kf, out);
  }
}